// Round 5
// baseline (2926.085 us; speedup 1.0000x reference)
//
#include <hip/hip_runtime.h>
#include <stdint.h>

#define Tsz 512
#define Dsz 256
#define NCYC 516      // depth 5: van(t=n) l1(n-1) l2(n-2) gx(n-3) gru(n-4)
#define GR 16         // batch rows per block
#define P_X 264       // LDS pitches (f16 units), +8 pad -> 2-way bank alias (free)
#define P_H1 104
#define P_H2 136
#define P_H3 72

typedef _Float16 f16x8 __attribute__((ext_vector_type(8)));
typedef float f32x4 __attribute__((ext_vector_type(4)));

union UHp { uint32_t u; _Float16 s[2]; };
__device__ __forceinline__ uint32_t packh2(float a, float b) {
    UHp x; x.s[0] = (_Float16)a; x.s[1] = (_Float16)b; return x.u;
}
__device__ __forceinline__ float fsig(float x)  { return 1.0f / (1.0f + __expf(-x)); }
__device__ __forceinline__ float ftanh(float x) { return 2.0f / (1.0f + __expf(-2.0f * x)) - 1.0f; }

#define MM(A, B, C) __builtin_amdgcn_mfma_f32_16x16x32_f16((A), (B), (C), 0, 0, 0)

// B-fragment gather: lane holds B[k0 + j][col], j=0..7 (k0 = kt*32 + (lane>>4)*8)
__device__ __forceinline__ f16x8 bfrag(const float* W, int ldw, int k0, int col) {
    f16x8 b;
#pragma unroll
    for (int j = 0; j < 8; ++j) b[j] = (_Float16)W[(size_t)(k0 + j) * ldw + col];
    return b;
}

// 4x4 transpose within lane-quads + pack to 4 f16.
// In: lane e=lane&3 holds v[p] = M[row g*4+p][col base+4q+e].
// Out: uint2 = 4 f16 for row g*4+e, cols base+4q+0..3.
__device__ __forceinline__ uint2 xpose4(float v0, float v1, float v2, float v3, int e) {
    const bool o1 = e & 1;
    float t1 = __shfl_xor(o1 ? v0 : v1, 1);
    float t3 = __shfl_xor(o1 ? v2 : v3, 1);
    if (o1) { v0 = t1; v2 = t3; } else { v1 = t1; v3 = t3; }
    const bool o2 = e & 2;
    float t2 = __shfl_xor(o2 ? v0 : v2, 2);
    float t4 = __shfl_xor(o2 ? v1 : v3, 2);
    if (o2) { v0 = t2; v1 = t4; } else { v2 = t2; v3 = t4; }
    uint2 r; r.x = packh2(v0, v1); r.y = packh2(v2, v3);
    return r;
}

// Block = 16 batch rows, 512 threads = 8 waves, grid 32 (one CU per block).
//  w0: van   w1,w2: lstm1 (u-tiles 0,1 / 2,3)   w3,w4: lstm2   w5: gru gx
//  w6: gru recurrent (wave-sync internal zr->a)  w7: pixel fetch+convert
// All inter-stage activations double-buffered in LDS f16; one barrier/iter.
__global__ __launch_bounds__(512, 2) void rnn_mfma(
    const float* __restrict__ pix,
    const float* __restrict__ van_wi, const float* __restrict__ van_bi,
    const float* __restrict__ van_wh, const float* __restrict__ van_bh,
    const float* __restrict__ w1g, const float* __restrict__ b1g,
    const float* __restrict__ w2g, const float* __restrict__ b2g,
    const float* __restrict__ gwi, const float* __restrict__ gwh,
    const float* __restrict__ gb,
    const float* __restrict__ mw1, const float* __restrict__ mb1,
    const float* __restrict__ mw2, const float* __restrict__ mb2,
    const float* __restrict__ mw3, const float* __restrict__ mb3,
    const float* __restrict__ sf,
    float* __restrict__ out)
{
    const int tid  = threadIdx.x;
    const int wv   = tid >> 6;
    const int lane = tid & 63;
    const int gr0  = blockIdx.x * GR;

    const int rw  = lane & 15;          // A-frag row
    const int kg8 = (lane >> 4) * 8;    // A/B-frag k-group base
    const int c16 = lane & 15;          // B/C col within tile
    const int g   = lane >> 4;          // C row-group
    const int e   = lane & 3;           // quad element
    const int q   = (lane >> 2) & 3;    // quad index
    const int rw7 = lane >> 2, ch = lane & 3;   // pixel wave mapping

    __shared__ __align__(16) _Float16 xls[2][GR * P_X];
    __shared__ __align__(16) _Float16 hc1[2][GR * P_H1];   // [h0(0:32)|h1(32:96)]
    __shared__ __align__(16) _Float16 hc2[2][GR * P_H2];   // [h1(0:64)|h2(64:128)]
    __shared__ __align__(16) float    gxf[2][12 * 256];    // raw gx C-frags [tile][lane][reg]
    __shared__ __align__(16) _Float16 h3A[GR * P_H3];      // gru-private (wave-sync)
    __shared__ __align__(16) _Float16 rhA[GR * P_H3];
    __shared__ float sHf[GR][64];
    __shared__ float sT[GR][64];
    __shared__ float sP[GR][12];

    f16x8 wfr[32];            // role-unioned B-fragments (max: lstm2 = 32)
    float bs[12];             // role biases (per-col, broadcast over rows)
    float st[16];             // cross-iter state: lstm c (8) / gru h3 (16)
    float4 px[16];            // pixel prefetch regs (w7 only)
#pragma unroll
    for (int i = 0; i < 12; ++i) bs[i] = 0.f;
#pragma unroll
    for (int i = 0; i < 16; ++i) st[i] = 0.f;

    const float* pbase = pix + ((size_t)(gr0 + rw7) * Tsz) * Dsz + ch * 64;

    // ---------------- per-role weight load (once) ----------------
    if (wv == 0) {                       // van: x@wvi + h0@wvh + b
#pragma unroll
        for (int nt = 0; nt < 2; ++nt) {
#pragma unroll
            for (int kt = 0; kt < 8; ++kt)
                wfr[nt * 8 + kt] = bfrag(van_wi, 32, kt * 32 + kg8, nt * 16 + c16);
            wfr[16 + nt] = bfrag(van_wh, 32, kg8, nt * 16 + c16);
            bs[nt] = van_bi[nt * 16 + c16] + van_bh[nt * 16 + c16];
        }
    } else if (wv <= 2) {                // lstm1: K=96, u-tiles 2(wv-1), 2(wv-1)+1
        const int uh = wv - 1;
#pragma unroll
        for (int lu = 0; lu < 2; ++lu) {
            const int ut = 2 * uh + lu;
#pragma unroll
            for (int gt = 0; gt < 4; ++gt) {
#pragma unroll
                for (int kt = 0; kt < 3; ++kt)
                    wfr[lu * 12 + gt * 3 + kt] =
                        bfrag(w1g, 256, kt * 32 + kg8, gt * 64 + ut * 16 + c16);
                bs[lu * 4 + gt] = b1g[gt * 64 + ut * 16 + c16];
            }
        }
    } else if (wv <= 4) {                // lstm2: K=128
        const int uh = wv - 3;
#pragma unroll
        for (int lu = 0; lu < 2; ++lu) {
            const int ut = 2 * uh + lu;
#pragma unroll
            for (int gt = 0; gt < 4; ++gt) {
#pragma unroll
                for (int kt = 0; kt < 4; ++kt)
                    wfr[lu * 16 + gt * 4 + kt] =
                        bfrag(w2g, 256, kt * 32 + kg8, gt * 64 + ut * 16 + c16);
                bs[lu * 4 + gt] = b2g[gt * 64 + ut * 16 + c16];
            }
        }
    } else if (wv == 5) {                // gx: h2 @ gru_wi + gb  (12 tiles, K=64)
#pragma unroll
        for (int t12 = 0; t12 < 12; ++t12) {
#pragma unroll
            for (int kt = 0; kt < 2; ++kt)
                wfr[t12 * 2 + kt] = bfrag(gwi, 192, kt * 32 + kg8, t12 * 16 + c16);
            bs[t12] = gb[t12 * 16 + c16];
        }
    } else if (wv == 6) {                // gru recurrent: gwh z / r / a
#pragma unroll
        for (int j = 0; j < 4; ++j) {
#pragma unroll
            for (int kt = 0; kt < 2; ++kt) {
                wfr[j * 2 + kt]      = bfrag(gwh, 192, kt * 32 + kg8, j * 16 + c16);
                wfr[8 + j * 2 + kt]  = bfrag(gwh, 192, kt * 32 + kg8, 64 + j * 16 + c16);
                wfr[16 + j * 2 + kt] = bfrag(gwh, 192, kt * 32 + kg8, 128 + j * 16 + c16);
            }
        }
    } else {                             // w7: pixel prologue x(0)->LDS buf1, x(1)->regs
#pragma unroll
        for (int m = 0; m < 16; ++m) px[m] = ((const float4*)pbase)[m];
        uint4* dst = (uint4*)(xls[1] + rw7 * P_X + ch * 64);
#pragma unroll
        for (int m = 0; m < 8; ++m) {
            uint4 w;
            w.x = packh2(px[2 * m].x, px[2 * m].y);
            w.y = packh2(px[2 * m].z, px[2 * m].w);
            w.z = packh2(px[2 * m + 1].x, px[2 * m + 1].y);
            w.w = packh2(px[2 * m + 1].z, px[2 * m + 1].w);
            dst[m] = w;
        }
#pragma unroll
        for (int m = 0; m < 16; ++m) px[m] = ((const float4*)(pbase + Dsz))[m];
    }

    // zero recurrent-activation buffers (both phases)
    for (int i = tid; i < 2 * GR * P_H1; i += 512) ((_Float16*)hc1)[i] = (_Float16)0.f;
    for (int i = tid; i < 2 * GR * P_H2; i += 512) ((_Float16*)hc2)[i] = (_Float16)0.f;
    for (int i = tid; i < GR * P_H3; i += 512) h3A[i] = (_Float16)0.f;
    __syncthreads();

    // ---------------- pipelined recurrence ----------------
    for (int n = 0; n < NCYC; ++n) {
        const int wb = n & 1, rb = wb ^ 1;

        if (wv == 0) {
            if (n < Tsz) {
                f16x8 Ax[8];
#pragma unroll
                for (int kt = 0; kt < 8; ++kt)
                    Ax[kt] = *(const f16x8*)(xls[rb] + rw * P_X + kt * 32 + kg8);
                f16x8 Ah = *(const f16x8*)(hc1[rb] + rw * P_H1 + kg8);
#pragma unroll
                for (int nt = 0; nt < 2; ++nt) {
                    f32x4 C = {bs[nt], bs[nt], bs[nt], bs[nt]};
#pragma unroll
                    for (int kt = 0; kt < 8; ++kt) C = MM(Ax[kt], wfr[nt * 8 + kt], C);
                    C = MM(Ah, wfr[16 + nt], C);
                    uint2 rpk = xpose4(fmaxf(C[0], 0.f), fmaxf(C[1], 0.f),
                                       fmaxf(C[2], 0.f), fmaxf(C[3], 0.f), e);
                    *(uint2*)(hc1[wb] + (g * 4 + e) * P_H1 + nt * 16 + 4 * q) = rpk;
                }
            }
        } else if (wv <= 2) {
            const int t = n - 1;
            if (0 <= t && t < Tsz) {
                f16x8 A1[3];
#pragma unroll
                for (int kt = 0; kt < 3; ++kt)
                    A1[kt] = *(const f16x8*)(hc1[rb] + rw * P_H1 + kt * 32 + kg8);
#pragma unroll
                for (int lu = 0; lu < 2; ++lu) {
                    const int ut = 2 * (wv - 1) + lu;
                    f32x4 Ci = {bs[lu*4+0], bs[lu*4+0], bs[lu*4+0], bs[lu*4+0]};
                    f32x4 Cg = {bs[lu*4+1], bs[lu*4+1], bs[lu*4+1], bs[lu*4+1]};
                    f32x4 Cf = {bs[lu*4+2], bs[lu*4+2], bs[lu*4+2], bs[lu*4+2]};
                    f32x4 Co = {bs[lu*4+3], bs[lu*4+3], bs[lu*4+3], bs[lu*4+3]};
#pragma unroll
                    for (int kt = 0; kt < 3; ++kt) {
                        Ci = MM(A1[kt], wfr[lu * 12 + 0 + kt], Ci);
                        Cg = MM(A1[kt], wfr[lu * 12 + 3 + kt], Cg);
                        Cf = MM(A1[kt], wfr[lu * 12 + 6 + kt], Cf);
                        Co = MM(A1[kt], wfr[lu * 12 + 9 + kt], Co);
                    }
                    float hv[4];
#pragma unroll
                    for (int p = 0; p < 4; ++p) {
                        float cc = fsig(Cf[p] + 1.f) * st[lu * 4 + p]
                                 + fsig(Ci[p]) * ftanh(Cg[p]);
                        st[lu * 4 + p] = cc;
                        hv[p] = fsig(Co[p]) * ftanh(cc);
                    }
                    uint2 rpk = xpose4(hv[0], hv[1], hv[2], hv[3], e);
                    *(uint2*)(hc1[wb] + (g * 4 + e) * P_H1 + 32 + ut * 16 + 4 * q) = rpk;
                    *(uint2*)(hc2[wb] + (g * 4 + e) * P_H2 + ut * 16 + 4 * q) = rpk;
                }
            }
        } else if (wv <= 4) {
            const int t = n - 2;
            if (0 <= t && t < Tsz) {
                f16x8 A2[4];
#pragma unroll
                for (int kt = 0; kt < 4; ++kt)
                    A2[kt] = *(const f16x8*)(hc2[rb] + rw * P_H2 + kt * 32 + kg8);
#pragma unroll
                for (int lu = 0; lu < 2; ++lu) {
                    const int ut = 2 * (wv - 3) + lu;
                    f32x4 Ci = {bs[lu*4+0], bs[lu*4+0], bs[lu*4+0], bs[lu*4+0]};
                    f32x4 Cg = {bs[lu*4+1], bs[lu*4+1], bs[lu*4+1], bs[lu*4+1]};
                    f32x4 Cf = {bs[lu*4+2], bs[lu*4+2], bs[lu*4+2], bs[lu*4+2]};
                    f32x4 Co = {bs[lu*4+3], bs[lu*4+3], bs[lu*4+3], bs[lu*4+3]};
#pragma unroll
                    for (int kt = 0; kt < 4; ++kt) {
                        Ci = MM(A2[kt], wfr[lu * 16 + 0 + kt], Ci);
                        Cg = MM(A2[kt], wfr[lu * 16 + 4 + kt], Cg);
                        Cf = MM(A2[kt], wfr[lu * 16 + 8 + kt], Cf);
                        Co = MM(A2[kt], wfr[lu * 16 + 12 + kt], Co);
                    }
                    float hv[4];
#pragma unroll
                    for (int p = 0; p < 4; ++p) {
                        float cc = fsig(Cf[p] + 1.f) * st[lu * 4 + p]
                                 + fsig(Ci[p]) * ftanh(Cg[p]);
                        st[lu * 4 + p] = cc;
                        hv[p] = fsig(Co[p]) * ftanh(cc);
                    }
                    uint2 rpk = xpose4(hv[0], hv[1], hv[2], hv[3], e);
                    *(uint2*)(hc2[wb] + (g * 4 + e) * P_H2 + 64 + ut * 16 + 4 * q) = rpk;
                }
            }
        } else if (wv == 5) {
            const int t = n - 3;
            if (0 <= t && t < Tsz) {
                f16x8 Ag[2];
#pragma unroll
                for (int kt = 0; kt < 2; ++kt)
                    Ag[kt] = *(const f16x8*)(hc2[rb] + rw * P_H2 + 64 + kt * 32 + kg8);
#pragma unroll
                for (int t12 = 0; t12 < 12; ++t12) {
                    f32x4 C = {bs[t12], bs[t12], bs[t12], bs[t12]};
                    C = MM(Ag[0], wfr[t12 * 2 + 0], C);
                    C = MM(Ag[1], wfr[t12 * 2 + 1], C);
                    *(f32x4*)(gxf[wb] + t12 * 256 + lane * 4) = C;
                }
            }
        } else if (wv == 6) {
            const int t = n - 4;
            if (0 <= t && t < Tsz) {
                f16x8 Ah[2];
#pragma unroll
                for (int kt = 0; kt < 2; ++kt)
                    Ah[kt] = *(const f16x8*)(h3A + rw * P_H3 + kt * 32 + kg8);
                float z_[16];
#pragma unroll
                for (int j = 0; j < 4; ++j) {
                    f32x4 Cz = *(const f32x4*)(gxf[rb] + j * 256 + lane * 4);
                    f32x4 Cr = *(const f32x4*)(gxf[rb] + (4 + j) * 256 + lane * 4);
#pragma unroll
                    for (int kt = 0; kt < 2; ++kt) {
                        Cz = MM(Ah[kt], wfr[j * 2 + kt], Cz);
                        Cr = MM(Ah[kt], wfr[8 + j * 2 + kt], Cr);
                    }
                    float rh[4];
#pragma unroll
                    for (int p = 0; p < 4; ++p) {
                        z_[j * 4 + p] = fsig(Cz[p]);
                        rh[p] = fsig(Cr[p]) * st[j * 4 + p];
                    }
                    uint2 rpk = xpose4(rh[0], rh[1], rh[2], rh[3], e);
                    *(uint2*)(rhA + (g * 4 + e) * P_H3 + j * 16 + 4 * q) = rpk;
                }
                asm volatile("s_waitcnt lgkmcnt(0)" ::: "memory");
                __builtin_amdgcn_sched_barrier(0);
                f16x8 Ar[2];
#pragma unroll
                for (int kt = 0; kt < 2; ++kt)
                    Ar[kt] = *(const f16x8*)(rhA + rw * P_H3 + kt * 32 + kg8);
#pragma unroll
                for (int j = 0; j < 4; ++j) {
                    f32x4 Ca = *(const f32x4*)(gxf[rb] + (8 + j) * 256 + lane * 4);
                    Ca = MM(Ar[0], wfr[16 + j * 2 + 0], Ca);
                    Ca = MM(Ar[1], wfr[16 + j * 2 + 1], Ca);
                    float hn[4];
#pragma unroll
                    for (int p = 0; p < 4; ++p) {
                        float av = ftanh(Ca[p]);
                        float z  = z_[j * 4 + p];
                        float h  = st[j * 4 + p];
                        h = (1.f - z) * h + z * av;
                        st[j * 4 + p] = h;
                        hn[p] = h;
                    }
                    uint2 rpk = xpose4(hn[0], hn[1], hn[2], hn[3], e);
                    *(uint2*)(h3A + (g * 4 + e) * P_H3 + j * 16 + 4 * q) = rpk;
                }
            }
        } else {
            if (n + 1 < Tsz) {
                uint4* dst = (uint4*)(xls[wb] + rw7 * P_X + ch * 64);
#pragma unroll
                for (int m = 0; m < 8; ++m) {
                    uint4 w;
                    w.x = packh2(px[2 * m].x, px[2 * m].y);
                    w.y = packh2(px[2 * m].z, px[2 * m].w);
                    w.z = packh2(px[2 * m + 1].x, px[2 * m + 1].y);
                    w.w = packh2(px[2 * m + 1].z, px[2 * m + 1].w);
                    dst[m] = w;
                }
            }
            if (n + 2 < Tsz) {
                const float4* src = (const float4*)(pbase + (size_t)(n + 2) * Dsz);
#pragma unroll
                for (int m = 0; m < 16; ++m) px[m] = src[m];
            }
        }
        __syncthreads();
    }

    // ---------------- MLP head (16 rows) ----------------
    if (wv == 6) {
#pragma unroll
        for (int j = 0; j < 4; ++j)
#pragma unroll
            for (int p = 0; p < 4; ++p)
                sHf[g * 4 + p][j * 16 + c16] = st[j * 4 + p];
    }
    __syncthreads();
    {
        const int hr = tid >> 5, hcx = tid & 31;
        float acc = mb1[hcx];
#pragma unroll
        for (int k = 0; k < 64; ++k) acc = fmaf(sHf[hr][k], mw1[k * 32 + hcx], acc);
        sT[hr][hcx] = fmaxf(acc, 0.f);
    }
    __syncthreads();
    {
        const int hr = tid >> 5, hcx = tid & 31;
        float acc = mb2[hcx];
#pragma unroll
        for (int k = 0; k < 32; ++k) acc = fmaf(sT[hr][k], mw2[k * 32 + hcx], acc);
        sT[hr][32 + hcx] = fmaxf(acc, 0.f);
    }
    __syncthreads();
    if (tid < 192) {
        const int hr = tid / 12, c = tid - 12 * hr;
        float acc = mb3[c];
#pragma unroll
        for (int k = 0; k < 32; ++k) acc = fmaf(sT[hr][32 + k], mw3[k * 12 + c], acc);
        sP[hr][c] = acc;
    }
    __syncthreads();
    if (tid < GR) {
        float acc = 0.f;
#pragma unroll
        for (int k = 0; k < 12; ++k) acc = fmaf(sP[tid][k], sf[k], acc);
        out[24 + gr0 + tid] = acc;
    }
    if (blockIdx.x == 0 && tid < 12) {
        out[tid] = sf[tid];
        out[12 + tid] = 1.0f;
    }
}

extern "C" void kernel_launch(void* const* d_in, const int* in_sizes, int n_in,
                              void* d_out, int out_size, void* d_ws, size_t ws_size,
                              hipStream_t stream) {
    (void)in_sizes; (void)n_in; (void)d_ws; (void)ws_size; (void)out_size;
    const float* pix    = (const float*)d_in[0];
    const float* van_wi = (const float*)d_in[1];
    const float* van_bi = (const float*)d_in[2];
    const float* van_wh = (const float*)d_in[3];
    const float* van_bh = (const float*)d_in[4];
    const float* w1     = (const float*)d_in[5];
    const float* b1     = (const float*)d_in[6];
    const float* w2     = (const float*)d_in[7];
    const float* b2     = (const float*)d_in[8];
    const float* gwi    = (const float*)d_in[9];
    const float* gwh    = (const float*)d_in[10];
    const float* gb     = (const float*)d_in[11];
    const float* mw1    = (const float*)d_in[12];
    const float* mb1    = (const float*)d_in[13];
    const float* mw2    = (const float*)d_in[14];
    const float* mb2    = (const float*)d_in[15];
    const float* mw3    = (const float*)d_in[16];
    const float* mb3    = (const float*)d_in[17];
    const float* sf     = (const float*)d_in[18];
    float* out = (float*)d_out;

    rnn_mfma<<<32, 512, 0, stream>>>(
        pix, van_wi, van_bi, van_wh, van_bh,
        w1, b1, w2, b2, gwi, gwh, gb,
        mw1, mb1, mw2, mb2, mw3, mb3, sf, out);
}